// Round 3
// baseline (445.501 us; speedup 1.0000x reference)
//
#include <hip/hip_runtime.h>
#include <math.h>

typedef unsigned short u16;
typedef unsigned int   u32;
typedef float  f32x4  __attribute__((ext_vector_type(4)));
typedef __bf16 bf16x8 __attribute__((ext_vector_type(8)));
typedef unsigned short u16x8 __attribute__((ext_vector_type(8)));

__device__ __forceinline__ float bf2f(u16 h) {
    union { u32 u; float f; } v; v.u = ((u32)h) << 16; return v.f;
}
__device__ __forceinline__ u16 f2bf(float f) {
    union { float f; u32 u; } v; v.f = f;
    u32 u = v.u;
    return (u16)((u + 0x7FFFu + ((u >> 16) & 1u)) >> 16);  // RNE
}

// async global->LDS, 16B per lane. LDS dest must be wave-uniform base + lane*16.
__device__ __forceinline__ void gload_lds16(const void* g, void* l) {
    __builtin_amdgcn_global_load_lds((const __attribute__((address_space(1))) void*)g,
                                     (__attribute__((address_space(3))) void*)l,
                                     16, 0, 0);
}

__device__ __forceinline__ void f_vmcnt8() { asm volatile("s_waitcnt vmcnt(8)" ::: "memory"); }
__device__ __forceinline__ void f_vmcnt4() { asm volatile("s_waitcnt vmcnt(4)" ::: "memory"); }
__device__ __forceinline__ void f_vmcnt0() { asm volatile("s_waitcnt vmcnt(0)" ::: "memory"); }

// ---------------------------------------------------------------------------
// Pipelined 256x256 GEMM (T2+T3+T4+T5): C = A[M][K] * Bt[N][K]^T, bf16.
// BK=32, 4-slot circular LDS (4 x (A 256x32 + B 256x32) = 128KB), counted
// vmcnt pipeline: while computing tile t, issue tile t+3; steady fence
// vmcnt(8) keeps 2 tiles in flight across the barrier (never 0 in-loop).
// T2 swizzle (round-2 fix): LDS[r][u] = G[r][u ^ swz(r)], swz(r)=(r>>1)&3.
// Stager pre-swizzles the GLOBAL source (global_load_lds dest must stay
// linear); reader XORs the k-unit. Without it, [256][32] rows (64B = 16
// banks) make each fragment ds_read_b128 an 8-way conflict (measured 3.5M
// SQ_LDS_BANK_CONFLICT in round 2); with it, lanes 0-7 cover all 32 banks
// once, lanes 8-15 repeat -> 2-way = free.
// 8 waves (2M x 4N), per-wave 128x64 = 8x4 frags of 16x16x32.
// MODE: 0 = store bf16, 1 = store bf16*scale, 3 = store bf16 gelu(acc+bias)
// ---------------------------------------------------------------------------
template<int MODE>
__global__ __launch_bounds__(512, 2)
void gemm256(const u16* __restrict__ A, const u16* __restrict__ Bt,
             u16* __restrict__ Ob, const float* __restrict__ bias,
             int lda, int ldb, int ldc, int K,
             long a_bstride, long b_bstride, long c_bstride, float scale)
{
    __shared__ __align__(16) u16 lds[4][2][256 * 32];   // [slot][A/B][r*32+k]

    const int bz = blockIdx.z;
    const u16* Ab = A  + (long)bz * a_bstride;
    const u16* Bb = Bt + (long)bz * b_bstride;
    const long cbase = (long)bz * c_bstride;

    const int tid  = threadIdx.x;
    const int lane = tid & 63;
    const int wid  = tid >> 6;
    const int wm   = wid >> 2;         // 0..1  (128 rows each)
    const int wn   = wid & 3;          // 0..3  (64 cols each)
    const long row0 = (long)blockIdx.x * 256;
    const long col0 = (long)blockIdx.y * 256;

    const int lr = lane & 15;          // frag row/col
    const int lk = lane >> 4;          // k-unit 0..3 (8 bf16)

    const int srow = tid >> 2;         // staging row 0..127 (i adds 128)
    const int sub  = tid & 3;          // staging 16B unit

    const int NT = K >> 5;             // K/32; all call-sites have NT >= 4

    f32x4 acc[8][4] = {{}};

    // ---- prologue: stage tiles 0,1,2 (12 loads/wave), wait for tile 0 ----
    for (int t0 = 0; t0 < 3; ++t0) {
        u16* dA = &lds[t0][0][0];
        u16* dB = &lds[t0][1][0];
        const int k0 = t0 * 32;
#pragma unroll
        for (int i = 0; i < 2; ++i) {
            const int r = i * 128 + srow;
            const int u = sub ^ ((r >> 1) & 3);
            gload_lds16(Ab + (row0 + r) * (long)lda + k0 + u * 8, dA + r * 32 + sub * 8);
        }
#pragma unroll
        for (int i = 0; i < 2; ++i) {
            const int r = i * 128 + srow;
            const int u = sub ^ ((r >> 1) & 3);
            gload_lds16(Bb + (col0 + r) * (long)ldb + k0 + u * 8, dB + r * 32 + sub * 8);
        }
    }
    f_vmcnt8();                         // 12 outstanding -> oldest 4 (tile 0) landed
    __builtin_amdgcn_s_barrier();
    __builtin_amdgcn_sched_barrier(0);

    // ---- main loop: 1 barrier per K-tile, counted vmcnt, loads span barriers ----
    for (int t = 0; t < NT; ++t) {
        const int s = t & 3;
        const u16* As = &lds[s][0][0];
        const u16* Bs = &lds[s][1][0];
        const int tp = t + 3;
        const bool issue = (tp < NT);

        // phase A: read B0-3 + A0-3 (swizzled), issue next A-half, MFMA m0-3
        bf16x8 bfr[4], afr[4];
#pragma unroll
        for (int n = 0; n < 4; ++n) {
            const int r = wn * 64 + n * 16 + lr;
            bfr[n] = *(const bf16x8*)(Bs + r * 32 + ((lk ^ ((r >> 1) & 3)) * 8));
        }
#pragma unroll
        for (int m = 0; m < 4; ++m) {
            const int r = wm * 128 + m * 16 + lr;
            afr[m] = *(const bf16x8*)(As + r * 32 + ((lk ^ ((r >> 1) & 3)) * 8));
        }
        if (issue) {
            u16* dA = &lds[tp & 3][0][0];
            const int k0p = tp * 32;
#pragma unroll
            for (int i = 0; i < 2; ++i) {
                const int r = i * 128 + srow;
                const int u = sub ^ ((r >> 1) & 3);
                gload_lds16(Ab + (row0 + r) * (long)lda + k0p + u * 8, dA + r * 32 + sub * 8);
            }
        }
        __builtin_amdgcn_s_setprio(1);
#pragma unroll
        for (int m = 0; m < 4; ++m)
#pragma unroll
            for (int n = 0; n < 4; ++n)
                acc[m][n] = __builtin_amdgcn_mfma_f32_16x16x32_bf16(
                                afr[m], bfr[n], acc[m][n], 0, 0, 0);
        __builtin_amdgcn_s_setprio(0);

        // phase B: read A4-7 (swizzled), issue next B-half, MFMA m4-7
#pragma unroll
        for (int m = 0; m < 4; ++m) {
            const int r = wm * 128 + (m + 4) * 16 + lr;
            afr[m] = *(const bf16x8*)(As + r * 32 + ((lk ^ ((r >> 1) & 3)) * 8));
        }
        if (issue) {
            u16* dB = &lds[tp & 3][1][0];
            const int k0p = tp * 32;
#pragma unroll
            for (int i = 0; i < 2; ++i) {
                const int r = i * 128 + srow;
                const int u = sub ^ ((r >> 1) & 3);
                gload_lds16(Bb + (col0 + r) * (long)ldb + k0p + u * 8, dB + r * 32 + sub * 8);
            }
        }
        __builtin_amdgcn_s_setprio(1);
#pragma unroll
        for (int m = 0; m < 4; ++m)
#pragma unroll
            for (int n = 0; n < 4; ++n)
                acc[m + 4][n] = __builtin_amdgcn_mfma_f32_16x16x32_bf16(
                                    afr[m], bfr[n], acc[m + 4][n], 0, 0, 0);
        __builtin_amdgcn_s_setprio(0);

        // fence: keep tiles t+2,t+3 in flight; guarantee t+1 resident
        if (t < NT - 3)       f_vmcnt8();
        else if (t == NT - 3) f_vmcnt4();
        else if (t == NT - 2) f_vmcnt0();
        if (t < NT - 1) {
            __builtin_amdgcn_s_barrier();
            __builtin_amdgcn_sched_barrier(0);
        }
    }

    // ---- epilogue: C/D layout col=lane&15, row=(lane>>4)*4+reg ----
#pragma unroll
    for (int m = 0; m < 8; ++m) {
#pragma unroll
        for (int n = 0; n < 4; ++n) {
#pragma unroll
            for (int j = 0; j < 4; ++j) {
                const long row = row0 + wm * 128 + m * 16 + lk * 4 + j;
                const long col = col0 + wn * 64 + n * 16 + lr;
                const long idx = cbase + row * (long)ldc + col;
                const float v = acc[m][n][j];
                if (MODE == 0) {
                    Ob[idx] = f2bf(v);
                } else if (MODE == 1) {
                    Ob[idx] = f2bf(v * scale);
                } else {
                    const float tt = v + bias[col];
                    Ob[idx] = f2bf(0.5f * tt * (1.0f + erff(tt * 0.70710678118654752f)));
                }
            }
        }
    }
}

// ---------------------------------------------------------------------------
// 128x128 GEMM (proven structure, stride-parameterized).
// MODE: 0 = store bf16, 2 = f32 acc+bias[col]+res[idx]
// ---------------------------------------------------------------------------
template<int MODE>
__global__ __launch_bounds__(256, 2)
void gemm_bt(const u16* __restrict__ A, const u16* __restrict__ Bt,
             u16* __restrict__ Ob, float* __restrict__ Of,
             const float* __restrict__ bias, const float* __restrict__ res,
             int lda, int ldb, int ldc, int K,
             long a_bstride, long b_bstride, long c_bstride)
{
    __shared__ __align__(16) u16 As[128 * 32];
    __shared__ __align__(16) u16 Bs[128 * 32];

    const int bz = blockIdx.z;
    const u16* Ab = A + (long)bz * a_bstride;
    const u16* Bb = Bt + (long)bz * b_bstride;
    const long cbase = (long)bz * c_bstride;

    const int tid  = threadIdx.x;
    const int lane = tid & 63;
    const int wave = tid >> 6;
    const int wr = (wave >> 1) * 64;
    const int wc = (wave & 1) * 64;
    const long row0 = (long)blockIdx.x * 128;
    const long col0 = (long)blockIdx.y * 128;

    const int lr = lane & 15;
    const int lk = lane >> 4;
    const int srow = tid >> 2;
    const int sub  = tid & 3;

    f32x4 acc[4][4] = {{}};

    for (int k0 = 0; k0 < K; k0 += 32) {
#pragma unroll
        for (int p = 0; p < 2; ++p) {
            const int r = p * 64 + srow;
            const int u = sub ^ ((r >> 1) & 3);          // pre-swizzled source
            gload_lds16(Ab + (row0 + r) * (long)lda + k0 + u * 8, As + r * 32 + sub * 8);
            gload_lds16(Bb + (col0 + r) * (long)ldb + k0 + u * 8, Bs + r * 32 + sub * 8);
        }
        __syncthreads();

        bf16x8 af[4], bfr[4];
#pragma unroll
        for (int m = 0; m < 4; ++m) {
            const int r = wr + m * 16 + lr;
            af[m] = *(const bf16x8*)(As + r * 32 + ((lk ^ ((r >> 1) & 3)) * 8));
        }
#pragma unroll
        for (int n = 0; n < 4; ++n) {
            const int r = wc + n * 16 + lr;
            bfr[n] = *(const bf16x8*)(Bs + r * 32 + ((lk ^ ((r >> 1) & 3)) * 8));
        }
#pragma unroll
        for (int m = 0; m < 4; ++m)
#pragma unroll
            for (int n = 0; n < 4; ++n)
                acc[m][n] = __builtin_amdgcn_mfma_f32_16x16x32_bf16(
                                af[m], bfr[n], acc[m][n], 0, 0, 0);
        __syncthreads();
    }

#pragma unroll
    for (int m = 0; m < 4; ++m) {
#pragma unroll
        for (int n = 0; n < 4; ++n) {
#pragma unroll
            for (int j = 0; j < 4; ++j) {
                const long row = row0 + wr + m * 16 + lk * 4 + j;
                const long col = col0 + wc + n * 16 + lr;
                const long idx = cbase + row * (long)ldc + col;
                const float v = acc[m][n][j];
                if (MODE == 0) {
                    Ob[idx] = f2bf(v);
                } else {
                    Of[idx] = v + bias[col] + res[idx];
                }
            }
        }
    }
}

// ---------------------------------------------------------------------------
// transpose + cast fp32 -> bf16 : in[R][C] -> out[C][R]
// ---------------------------------------------------------------------------
__global__ __launch_bounds__(256)
void transpose_cast_f32(const float* __restrict__ in, u16* __restrict__ out,
                        int R, int C)
{
    __shared__ u16 tile[32][33];
    const int c0 = blockIdx.x * 32, r0 = blockIdx.y * 32;
    const int tx = threadIdx.x, ty = threadIdx.y;   // 32 x 8
#pragma unroll
    for (int j = 0; j < 4; ++j) {
        const int r = ty + j * 8;
        tile[r][tx] = f2bf(in[(long)(r0 + r) * C + c0 + tx]);
    }
    __syncthreads();
#pragma unroll
    for (int j = 0; j < 4; ++j) {
        const int c = ty + j * 8;
        out[(long)(c0 + c) * R + r0 + tx] = tile[tx][c];
    }
}

// bf16 strided transpose with batch: in[z][R][ld_in] -> out[z][C][R]
__global__ __launch_bounds__(256)
void transpose_b16(const u16* __restrict__ in, u16* __restrict__ out,
                   int R, int C, int ld_in, long in_bstride, long out_bstride)
{
    __shared__ u16 tile[32][33];
    in  += (long)blockIdx.z * in_bstride;
    out += (long)blockIdx.z * out_bstride;
    const int c0 = blockIdx.x * 32, r0 = blockIdx.y * 32;
    const int tx = threadIdx.x, ty = threadIdx.y;
#pragma unroll
    for (int j = 0; j < 4; ++j) {
        const int r = ty + j * 8;
        tile[r][tx] = in[(long)(r0 + r) * ld_in + c0 + tx];
    }
    __syncthreads();
#pragma unroll
    for (int j = 0; j < 4; ++j) {
        const int c = ty + j * 8;
        out[(long)(c0 + c) * R + r0 + tx] = tile[tx][c];
    }
}

// ---------------------------------------------------------------------------
// LayerNorm over D=768, one block (256 thr) per row; out bf16.
// ---------------------------------------------------------------------------
__global__ __launch_bounds__(256)
void layernorm_k(const float* __restrict__ x, const float* __restrict__ g,
                 const float* __restrict__ b, u16* __restrict__ out, int D)
{
    const long row = blockIdx.x;
    const float* xr = x + row * D;
    const int tid = threadIdx.x;
    float v[3];
    float s = 0.f, s2 = 0.f;
#pragma unroll
    for (int i = 0; i < 3; ++i) {
        v[i] = xr[tid + i * 256];
        s += v[i]; s2 += v[i] * v[i];
    }
#pragma unroll
    for (int o = 32; o > 0; o >>= 1) {
        s  += __shfl_down(s,  o);
        s2 += __shfl_down(s2, o);
    }
    __shared__ float ps[4], ps2[4], st[2];
    const int wave = tid >> 6, lane = tid & 63;
    if (lane == 0) { ps[wave] = s; ps2[wave] = s2; }
    __syncthreads();
    if (tid == 0) {
        const float a  = ps[0] + ps[1] + ps[2] + ps[3];
        const float a2 = ps2[0] + ps2[1] + ps2[2] + ps2[3];
        const float mu = a / (float)D;
        const float var = a2 / (float)D - mu * mu;
        st[0] = mu;
        st[1] = rsqrtf(var + 1e-8f);
    }
    __syncthreads();
    const float mu = st[0], rs = st[1];
#pragma unroll
    for (int i = 0; i < 3; ++i) {
        const int c = tid + i * 256;
        out[row * D + c] = f2bf((v[i] - mu) * rs * g[c] + b[c]);
    }
}

// ---------------------------------------------------------------------------
// Row softmax in-place over bf16 rows of length 4096, vectorized 16B/lane.
// ---------------------------------------------------------------------------
__global__ __launch_bounds__(256)
void softmax_rows(u16* __restrict__ S, int L)
{
    u16* row = S + (long)blockIdx.x * L;
    const int tid = threadIdx.x;
    const int wave = tid >> 6, lane = tid & 63;
    u16x8 h0 = *(const u16x8*)(row + tid * 16);
    u16x8 h1 = *(const u16x8*)(row + tid * 16 + 8);
    float v[16];
#pragma unroll
    for (int i = 0; i < 8; ++i) { v[i] = bf2f(h0[i]); v[8 + i] = bf2f(h1[i]); }

    float m = -1e30f;
#pragma unroll
    for (int i = 0; i < 16; ++i) m = fmaxf(m, v[i]);
#pragma unroll
    for (int o = 32; o > 0; o >>= 1) m = fmaxf(m, __shfl_xor(m, o));
    __shared__ float pm[4], pl[4];
    if (lane == 0) pm[wave] = m;
    __syncthreads();
    m = fmaxf(fmaxf(pm[0], pm[1]), fmaxf(pm[2], pm[3]));

    float l = 0.f;
#pragma unroll
    for (int i = 0; i < 16; ++i) { v[i] = expf(v[i] - m); l += v[i]; }
#pragma unroll
    for (int o = 32; o > 0; o >>= 1) l += __shfl_xor(l, o);
    if (lane == 0) pl[wave] = l;
    __syncthreads();
    l = pl[0] + pl[1] + pl[2] + pl[3];
    const float inv = 1.0f / l;
#pragma unroll
    for (int i = 0; i < 8; ++i) { h0[i] = f2bf(v[i] * inv); h1[i] = f2bf(v[8 + i] * inv); }
    *(u16x8*)(row + tid * 16)     = h0;
    *(u16x8*)(row + tid * 16 + 8) = h1;
}

// ---------------------------------------------------------------------------
extern "C" void kernel_launch(void* const* d_in, const int* in_sizes, int n_in,
                              void* d_out, int out_size, void* d_ws, size_t ws_size,
                              hipStream_t stream)
{
    (void)in_sizes; (void)n_in; (void)out_size; (void)ws_size;
    const int B = 2, S = 4096, D = 768, F = 3072;
    const int BS = B * S;                       // 8192
    const int QKV = 3 * D;                      // 2304

    const float* x    = (const float*)d_in[0];
    // d_in[1] = mask: all ones -> no-op
    const float* ln1g = (const float*)d_in[2];
    const float* ln1b = (const float*)d_in[3];
    const float* wq   = (const float*)d_in[4];
    const float* wk   = (const float*)d_in[5];
    const float* wv   = (const float*)d_in[6];
    const float* wo   = (const float*)d_in[7];
    const float* bo   = (const float*)d_in[8];
    const float* ln2g = (const float*)d_in[9];
    const float* ln2b = (const float*)d_in[10];
    const float* w1   = (const float*)d_in[11];
    const float* b1   = (const float*)d_in[12];
    const float* w2   = (const float*)d_in[13];
    const float* b2   = (const float*)d_in[14];

    char* p = (char*)d_ws;
    auto alloc = [&](size_t bytes) {
        char* r = p; p += (bytes + 255) & ~(size_t)255; return r;
    };
    u16*  xn    = (u16*)alloc((size_t)BS * D * 2);      // LN1 out -> attn_out -> LN2 out
    u16*  qkv   = (u16*)alloc((size_t)BS * QKV * 2);    // [8192][2304] fused q|k|v
    u16*  Sb    = (u16*)alloc((size_t)B * S * S * 2);   // scores/P, later h [8192][3072]
    u16*  wqkvt = (u16*)alloc((size_t)3 * D * D * 2);   // [2304][768]
    u16*  wot   = (u16*)alloc((size_t)D * D * 2);
    u16*  w1t   = (u16*)alloc((size_t)D * F * 2);       // [3072][768]
    u16*  w2t   = (u16*)alloc((size_t)D * F * 2);       // [768][3072]
    float* xmid = (float*)alloc((size_t)BS * D * 4);
    u16*  vt    = (u16*)xmid;   // [2][768][4096]; dead before xmid is written

    const dim3 tt(32, 8);
    transpose_cast_f32<<<dim3(D/32, D/32, 1), tt, 0, stream>>>(wq, wqkvt,            D, D);
    transpose_cast_f32<<<dim3(D/32, D/32, 1), tt, 0, stream>>>(wk, wqkvt + D * D,    D, D);
    transpose_cast_f32<<<dim3(D/32, D/32, 1), tt, 0, stream>>>(wv, wqkvt + 2 * D * D,D, D);
    transpose_cast_f32<<<dim3(D/32, D/32, 1), tt, 0, stream>>>(wo, wot, D, D);
    transpose_cast_f32<<<dim3(F/32, D/32, 1), tt, 0, stream>>>(w1, w1t, D, F);
    transpose_cast_f32<<<dim3(D/32, F/32, 1), tt, 0, stream>>>(w2, w2t, F, D);

    // LN1
    layernorm_k<<<BS, 256, 0, stream>>>(x, ln1g, ln1b, xn, D);

    // fused QKV: [8192][768] x [2304][768]^T -> [8192][2304]
    gemm256<0><<<dim3(BS/256, QKV/256, 1), 512, 0, stream>>>(
        xn, wqkvt, qkv, nullptr, D, D, QKV, D, 0, 0, 0, 1.f);

    // scores = q @ k^T / sqrt(D)  per batch -> Sb
    const float scl = 0.03608439182435161f;   // 1/sqrt(768)
    gemm256<1><<<dim3(S/256, S/256, B), 512, 0, stream>>>(
        qkv, qkv + D, Sb, nullptr, QKV, QKV, S, D,
        (long)S * QKV, (long)S * QKV, (long)S * S, scl);

    // v^T per batch: qkv v-slice [4096][2304-strided] -> vt [768][4096]
    transpose_b16<<<dim3(D/32, S/32, B), tt, 0, stream>>>(
        qkv + 2 * D, vt, S, D, QKV, (long)S * QKV, (long)D * S);

    // softmax rows in place
    softmax_rows<<<B * S, 256, 0, stream>>>(Sb, S);

    // attn_out = P @ V  -> xn (LN1 out is dead)
    gemm_bt<0><<<dim3(S/128, D/128, B), 256, 0, stream>>>(
        Sb, vt, xn, nullptr, nullptr, nullptr, S, S, D, S,
        (long)S * S, (long)D * S, (long)S * D);

    // x_mid = attn_out @ wo + bo + x  (fp32)
    gemm_bt<2><<<dim3(BS/128, D/128, 1), 256, 0, stream>>>(
        xn, wot, nullptr, xmid, bo, x, D, D, D, D, 0, 0, 0);

    // LN2 -> xn
    layernorm_k<<<BS, 256, 0, stream>>>(xmid, ln2g, ln2b, xn, D);

    // h = gelu(xn @ w1 + b1) -> Sb [8192][3072]
    gemm256<3><<<dim3(BS/256, F/256, 1), 512, 0, stream>>>(
        xn, w1t, Sb, b1, D, D, F, D, 0, 0, 0, 1.f);

    // out = h @ w2 + b2 + xmid  (fp32 -> d_out)
    gemm_bt<2><<<dim3(BS/128, D/128, 1), 256, 0, stream>>>(
        Sb, w2t, nullptr, (float*)d_out, b2, xmid, F, F, D, F, 0, 0, 0);
}

// Round 4
// 440.634 us; speedup vs baseline: 1.0110x; 1.0110x over previous
//
#include <hip/hip_runtime.h>
#include <math.h>

typedef unsigned short u16;
typedef unsigned int   u32;
typedef float  f32x4  __attribute__((ext_vector_type(4)));
typedef __bf16 bf16x8 __attribute__((ext_vector_type(8)));
typedef unsigned short u16x8 __attribute__((ext_vector_type(8)));

__device__ __forceinline__ float bf2f(u16 h) {
    union { u32 u; float f; } v; v.u = ((u32)h) << 16; return v.f;
}
__device__ __forceinline__ u16 f2bf(float f) {
    union { float f; u32 u; } v; v.f = f;
    u32 u = v.u;
    return (u16)((u + 0x7FFFu + ((u >> 16) & 1u)) >> 16);  // RNE
}

// async global->LDS, 16B per lane. LDS dest must be wave-uniform base + lane*16.
__device__ __forceinline__ void gload_lds16(const void* g, void* l) {
    __builtin_amdgcn_global_load_lds((const __attribute__((address_space(1))) void*)g,
                                     (__attribute__((address_space(3))) void*)l,
                                     16, 0, 0);
}

#define SBAR __builtin_amdgcn_sched_barrier(0)
#define WBAR __builtin_amdgcn_s_barrier()
#define MF(a, b, c) __builtin_amdgcn_mfma_f32_16x16x32_bf16((a), (b), (c), 0, 0, 0)

// ---------------------------------------------------------------------------
// 8-phase pipelined 256x256 GEMM (T2+T3+T4+T5, m201-style): C = A * Bt^T.
// BK=64. LDS = ring of 8 units x 16KB (unit = 256 rows x 32 k, bf16):
//   unit gu: tile gu>>2, kind gu&3 in {A-k0, B-k0, A-k1, B-k1}, slot gu&7.
// Per tile, 4 phases x {ds_read frags; stage 1 unit (2 gload_lds16/thread);
// barrier; MFMA x16 (setprio); barrier}. Phases: P0 = A(k0) m0-7 + B(k0)n01,
// P1 = B(k0)n23 (A-frags reused in regs), P2/P3 = same for k1.
// Ring safety: stage at phase p overwrites the unit consumed at phase p-1 of
// the CURRENT tile (slot (7+4t+p)-8 = 4t+p-1); consumption deadlines
// {A-k0:P0, B-k0:P1, A-k1:P2, B-k1:P3} hold, and the phase-(p-1) second
// barrier orders all waves' reads before the phase-p stage issue.
// Fence: one counted vmcnt per tile. Staged total after tile t = 11+4t units;
// tile t+1 needs units <= 4t+7; vmcnt(6) leaves 3 units (6 loads) in flight
// and confirms exactly through 4t+8 > 4t+7. Drain vmcnt(0) at t==NT-2.
// Never vmcnt(0) in steady state.
// k-octet XOR swizzle as in the proven 128x128 kernel (pre-swizzled global
// source, same XOR on ds_read; 2-way bank aliasing = free).
// MODE: 0 = store bf16, 1 = store bf16*scale, 3 = store bf16 gelu(acc+bias)
// ---------------------------------------------------------------------------
template<int MODE>
__global__ __launch_bounds__(512, 2)
void gemm256(const u16* __restrict__ A, const u16* __restrict__ Bt,
             u16* __restrict__ Ob, const float* __restrict__ bias,
             int lda, int ldb, int ldc, int K,
             long a_bstride, long b_bstride, long c_bstride, float scale)
{
    __shared__ __align__(16) u16 lds8[8][256 * 32];     // 8 x 16KB = 128KB

    const int bz = blockIdx.z;
    const u16* Ab = A  + (long)bz * a_bstride;
    const u16* Bb = Bt + (long)bz * b_bstride;
    const long cbase = (long)bz * c_bstride;

    const int tid  = threadIdx.x;
    const int lane = tid & 63;
    const int wid  = tid >> 6;
    const int wm   = wid >> 2;         // 0..1  (128 rows each)
    const int wn   = wid & 3;          // 0..3  (64 cols each)
    const long row0 = (long)blockIdx.x * 256;
    const long col0 = (long)blockIdx.y * 256;

    const int lr = lane & 15;          // frag row/col
    const int lk = lane >> 4;          // k-octet 0..3 (8 bf16)

    const int srow = tid >> 2;         // staging row 0..127 (i adds 128)
    const int sub  = tid & 3;          // staging 16B octet

    const int NT = K >> 6;             // K/64 (all call sites: K % 64 == 0, NT >= 2)
    const int NU = 4 * NT;

    f32x4 acc[8][4] = {{}};

    auto stage_unit = [&](int gu) {
        if (gu >= NU) return;
        const int tt   = gu >> 2;
        const int kind = gu & 3;                       // 0:A-k0 1:B-k0 2:A-k1 3:B-k1
        const long k0  = (long)tt * 64 + ((kind >> 1) & 1) * 32;
        const u16* src; long b0; long ld;
        if (kind & 1) { src = Bb; b0 = col0; ld = ldb; }
        else          { src = Ab; b0 = row0; ld = lda; }
        u16* dst = &lds8[gu & 7][0];
#pragma unroll
        for (int i = 0; i < 2; ++i) {
            const int r = i * 128 + srow;
            const int u = sub ^ ((r >> 1) & 3);        // pre-swizzled source octet
            gload_lds16(src + (b0 + r) * ld + k0 + u * 8, dst + r * 32 + sub * 8);
        }
    };
    auto rdA = [&](const u16* base, int m) -> bf16x8 {
        const int r = wm * 128 + m * 16 + lr;
        return *(const bf16x8*)(base + r * 32 + ((lk ^ ((r >> 1) & 3)) * 8));
    };
    auto rdB = [&](const u16* base, int n) -> bf16x8 {
        const int r = wn * 64 + n * 16 + lr;
        return *(const bf16x8*)(base + r * 32 + ((lk ^ ((r >> 1) & 3)) * 8));
    };

    // ---- prologue: stage units 0..6; confirm tile 0 (units 0..3) ----
    for (int gu0 = 0; gu0 < 7; ++gu0) stage_unit(gu0);
    asm volatile("s_waitcnt vmcnt(6)" ::: "memory");   // 14 loads -> 6 left = units 0..3 landed
    WBAR; SBAR;

    int gu = 7;
    for (int t = 0; t < NT; ++t) {
        const u16* uA0 = &lds8[(4 * t)     & 7][0];
        const u16* uB0 = &lds8[(4 * t + 1) & 7][0];
        const u16* uA1 = &lds8[(4 * t + 2) & 7][0];
        const u16* uB1 = &lds8[(4 * t + 3) & 7][0];

        bf16x8 af[8], bq[2];

        // ---------------- P0: A(k0) m0-7 + B(k0) n0-1 ----------------
#pragma unroll
        for (int m = 0; m < 8; ++m) af[m] = rdA(uA0, m);
        bq[0] = rdB(uB0, 0); bq[1] = rdB(uB0, 1);
        stage_unit(gu++);
        SBAR; WBAR; SBAR;
        __builtin_amdgcn_s_setprio(1);
#pragma unroll
        for (int m = 0; m < 8; ++m) {
            acc[m][0] = MF(af[m], bq[0], acc[m][0]);
            acc[m][1] = MF(af[m], bq[1], acc[m][1]);
        }
        __builtin_amdgcn_s_setprio(0);
        SBAR; WBAR;

        // ---------------- P1: B(k0) n2-3 (A reused) ----------------
        bq[0] = rdB(uB0, 2); bq[1] = rdB(uB0, 3);
        stage_unit(gu++);
        SBAR; WBAR; SBAR;
        __builtin_amdgcn_s_setprio(1);
#pragma unroll
        for (int m = 0; m < 8; ++m) {
            acc[m][2] = MF(af[m], bq[0], acc[m][2]);
            acc[m][3] = MF(af[m], bq[1], acc[m][3]);
        }
        __builtin_amdgcn_s_setprio(0);
        SBAR; WBAR;

        // ---------------- P2: A(k1) m0-7 + B(k1) n0-1 ----------------
#pragma unroll
        for (int m = 0; m < 8; ++m) af[m] = rdA(uA1, m);
        bq[0] = rdB(uB1, 0); bq[1] = rdB(uB1, 1);
        stage_unit(gu++);
        SBAR; WBAR; SBAR;
        __builtin_amdgcn_s_setprio(1);
#pragma unroll
        for (int m = 0; m < 8; ++m) {
            acc[m][0] = MF(af[m], bq[0], acc[m][0]);
            acc[m][1] = MF(af[m], bq[1], acc[m][1]);
        }
        __builtin_amdgcn_s_setprio(0);
        SBAR; WBAR;

        // ---------------- P3: B(k1) n2-3 ----------------
        bq[0] = rdB(uB1, 2); bq[1] = rdB(uB1, 3);
        stage_unit(gu++);
        SBAR; WBAR; SBAR;
        __builtin_amdgcn_s_setprio(1);
#pragma unroll
        for (int m = 0; m < 8; ++m) {
            acc[m][2] = MF(af[m], bq[0], acc[m][2]);
            acc[m][3] = MF(af[m], bq[1], acc[m][3]);
        }
        __builtin_amdgcn_s_setprio(0);
        SBAR;
        // tile-boundary fence: confirm next tile's 4 units, keep 3 in flight
        if (t < NT - 1) {
            if (t == NT - 2) asm volatile("s_waitcnt vmcnt(0)" ::: "memory");
            else             asm volatile("s_waitcnt vmcnt(6)" ::: "memory");
            WBAR; SBAR;
        }
    }

    // ---- epilogue: C/D layout col=lane&15, row=(lane>>4)*4+reg ----
#pragma unroll
    for (int m = 0; m < 8; ++m) {
#pragma unroll
        for (int n = 0; n < 4; ++n) {
#pragma unroll
            for (int j = 0; j < 4; ++j) {
                const long row = row0 + wm * 128 + m * 16 + lk * 4 + j;
                const long col = col0 + wn * 64 + n * 16 + lr;
                const long idx = cbase + row * (long)ldc + col;
                const float v = acc[m][n][j];
                if (MODE == 0) {
                    Ob[idx] = f2bf(v);
                } else if (MODE == 1) {
                    Ob[idx] = f2bf(v * scale);
                } else {
                    const float tt2 = v + bias[col];
                    Ob[idx] = f2bf(0.5f * tt2 * (1.0f + erff(tt2 * 0.70710678118654752f)));
                }
            }
        }
    }
}

// ---------------------------------------------------------------------------
// 128x128 GEMM (proven structure, stride-parameterized).
// MODE: 0 = store bf16, 2 = f32 acc+bias[col]+res[idx]
// ---------------------------------------------------------------------------
template<int MODE>
__global__ __launch_bounds__(256, 2)
void gemm_bt(const u16* __restrict__ A, const u16* __restrict__ Bt,
             u16* __restrict__ Ob, float* __restrict__ Of,
             const float* __restrict__ bias, const float* __restrict__ res,
             int lda, int ldb, int ldc, int K,
             long a_bstride, long b_bstride, long c_bstride)
{
    __shared__ __align__(16) u16 As[128 * 32];
    __shared__ __align__(16) u16 Bs[128 * 32];

    const int bz = blockIdx.z;
    const u16* Ab = A + (long)bz * a_bstride;
    const u16* Bb = Bt + (long)bz * b_bstride;
    const long cbase = (long)bz * c_bstride;

    const int tid  = threadIdx.x;
    const int lane = tid & 63;
    const int wave = tid >> 6;
    const int wr = (wave >> 1) * 64;
    const int wc = (wave & 1) * 64;
    const long row0 = (long)blockIdx.x * 128;
    const long col0 = (long)blockIdx.y * 128;

    const int lr = lane & 15;
    const int lk = lane >> 4;
    const int srow = tid >> 2;
    const int sub  = tid & 3;

    f32x4 acc[4][4] = {{}};

    for (int k0 = 0; k0 < K; k0 += 32) {
#pragma unroll
        for (int p = 0; p < 2; ++p) {
            const int r = p * 64 + srow;
            const int u = sub ^ ((r >> 1) & 3);          // pre-swizzled source
            gload_lds16(Ab + (row0 + r) * (long)lda + k0 + u * 8, As + r * 32 + sub * 8);
            gload_lds16(Bb + (col0 + r) * (long)ldb + k0 + u * 8, Bs + r * 32 + sub * 8);
        }
        __syncthreads();

        bf16x8 af[4], bfr[4];
#pragma unroll
        for (int m = 0; m < 4; ++m) {
            const int r = wr + m * 16 + lr;
            af[m] = *(const bf16x8*)(As + r * 32 + ((lk ^ ((r >> 1) & 3)) * 8));
        }
#pragma unroll
        for (int n = 0; n < 4; ++n) {
            const int r = wc + n * 16 + lr;
            bfr[n] = *(const bf16x8*)(Bs + r * 32 + ((lk ^ ((r >> 1) & 3)) * 8));
        }
#pragma unroll
        for (int m = 0; m < 4; ++m)
#pragma unroll
            for (int n = 0; n < 4; ++n)
                acc[m][n] = MF(af[m], bfr[n], acc[m][n]);
        __syncthreads();
    }

#pragma unroll
    for (int m = 0; m < 4; ++m) {
#pragma unroll
        for (int n = 0; n < 4; ++n) {
#pragma unroll
            for (int j = 0; j < 4; ++j) {
                const long row = row0 + wr + m * 16 + lk * 4 + j;
                const long col = col0 + wc + n * 16 + lr;
                const long idx = cbase + row * (long)ldc + col;
                const float v = acc[m][n][j];
                if (MODE == 0) {
                    Ob[idx] = f2bf(v);
                } else {
                    Of[idx] = v + bias[col] + res[idx];
                }
            }
        }
    }
}

// ---------------------------------------------------------------------------
// transpose + cast fp32 -> bf16 : in[R][C] -> out[C][R]
// ---------------------------------------------------------------------------
__global__ __launch_bounds__(256)
void transpose_cast_f32(const float* __restrict__ in, u16* __restrict__ out,
                        int R, int C)
{
    __shared__ u16 tile[32][33];
    const int c0 = blockIdx.x * 32, r0 = blockIdx.y * 32;
    const int tx = threadIdx.x, ty = threadIdx.y;   // 32 x 8
#pragma unroll
    for (int j = 0; j < 4; ++j) {
        const int r = ty + j * 8;
        tile[r][tx] = f2bf(in[(long)(r0 + r) * C + c0 + tx]);
    }
    __syncthreads();
#pragma unroll
    for (int j = 0; j < 4; ++j) {
        const int c = ty + j * 8;
        out[(long)(c0 + c) * R + r0 + tx] = tile[tx][c];
    }
}

// bf16 strided transpose with batch: in[z][R][ld_in] -> out[z][C][R]
__global__ __launch_bounds__(256)
void transpose_b16(const u16* __restrict__ in, u16* __restrict__ out,
                   int R, int C, int ld_in, long in_bstride, long out_bstride)
{
    __shared__ u16 tile[32][33];
    in  += (long)blockIdx.z * in_bstride;
    out += (long)blockIdx.z * out_bstride;
    const int c0 = blockIdx.x * 32, r0 = blockIdx.y * 32;
    const int tx = threadIdx.x, ty = threadIdx.y;
#pragma unroll
    for (int j = 0; j < 4; ++j) {
        const int r = ty + j * 8;
        tile[r][tx] = in[(long)(r0 + r) * ld_in + c0 + tx];
    }
    __syncthreads();
#pragma unroll
    for (int j = 0; j < 4; ++j) {
        const int c = ty + j * 8;
        out[(long)(c0 + c) * R + r0 + tx] = tile[tx][c];
    }
}

// ---------------------------------------------------------------------------
// LayerNorm over D=768, one block (256 thr) per row; out bf16.
// ---------------------------------------------------------------------------
__global__ __launch_bounds__(256)
void layernorm_k(const float* __restrict__ x, const float* __restrict__ g,
                 const float* __restrict__ b, u16* __restrict__ out, int D)
{
    const long row = blockIdx.x;
    const float* xr = x + row * D;
    const int tid = threadIdx.x;
    float v[3];
    float s = 0.f, s2 = 0.f;
#pragma unroll
    for (int i = 0; i < 3; ++i) {
        v[i] = xr[tid + i * 256];
        s += v[i]; s2 += v[i] * v[i];
    }
#pragma unroll
    for (int o = 32; o > 0; o >>= 1) {
        s  += __shfl_down(s,  o);
        s2 += __shfl_down(s2, o);
    }
    __shared__ float ps[4], ps2[4], st[2];
    const int wave = tid >> 6, lane = tid & 63;
    if (lane == 0) { ps[wave] = s; ps2[wave] = s2; }
    __syncthreads();
    if (tid == 0) {
        const float a  = ps[0] + ps[1] + ps[2] + ps[3];
        const float a2 = ps2[0] + ps2[1] + ps2[2] + ps2[3];
        const float mu = a / (float)D;
        const float var = a2 / (float)D - mu * mu;
        st[0] = mu;
        st[1] = rsqrtf(var + 1e-8f);
    }
    __syncthreads();
    const float mu = st[0], rs = st[1];
#pragma unroll
    for (int i = 0; i < 3; ++i) {
        const int c = tid + i * 256;
        out[row * D + c] = f2bf((v[i] - mu) * rs * g[c] + b[c]);
    }
}

// ---------------------------------------------------------------------------
// Row softmax in-place over bf16 rows of length 4096, vectorized 16B/lane.
// ---------------------------------------------------------------------------
__global__ __launch_bounds__(256)
void softmax_rows(u16* __restrict__ S, int L)
{
    u16* row = S + (long)blockIdx.x * L;
    const int tid = threadIdx.x;
    const int wave = tid >> 6, lane = tid & 63;
    u16x8 h0 = *(const u16x8*)(row + tid * 16);
    u16x8 h1 = *(const u16x8*)(row + tid * 16 + 8);
    float v[16];
#pragma unroll
    for (int i = 0; i < 8; ++i) { v[i] = bf2f(h0[i]); v[8 + i] = bf2f(h1[i]); }

    float m = -1e30f;
#pragma unroll
    for (int i = 0; i < 16; ++i) m = fmaxf(m, v[i]);
#pragma unroll
    for (int o = 32; o > 0; o >>= 1) m = fmaxf(m, __shfl_xor(m, o));
    __shared__ float pm[4], pl[4];
    if (lane == 0) pm[wave] = m;
    __syncthreads();
    m = fmaxf(fmaxf(pm[0], pm[1]), fmaxf(pm[2], pm[3]));

    float l = 0.f;
#pragma unroll
    for (int i = 0; i < 16; ++i) { v[i] = expf(v[i] - m); l += v[i]; }
#pragma unroll
    for (int o = 32; o > 0; o >>= 1) l += __shfl_xor(l, o);
    if (lane == 0) pl[wave] = l;
    __syncthreads();
    l = pl[0] + pl[1] + pl[2] + pl[3];
    const float inv = 1.0f / l;
#pragma unroll
    for (int i = 0; i < 8; ++i) { h0[i] = f2bf(v[i] * inv); h1[i] = f2bf(v[8 + i] * inv); }
    *(u16x8*)(row + tid * 16)     = h0;
    *(u16x8*)(row + tid * 16 + 8) = h1;
}

// ---------------------------------------------------------------------------
extern "C" void kernel_launch(void* const* d_in, const int* in_sizes, int n_in,
                              void* d_out, int out_size, void* d_ws, size_t ws_size,
                              hipStream_t stream)
{
    (void)in_sizes; (void)n_in; (void)out_size; (void)ws_size;
    const int B = 2, S = 4096, D = 768, F = 3072;
    const int BS = B * S;                       // 8192
    const int QKV = 3 * D;                      // 2304

    const float* x    = (const float*)d_in[0];
    // d_in[1] = mask: all ones -> no-op
    const float* ln1g = (const float*)d_in[2];
    const float* ln1b = (const float*)d_in[3];
    const float* wq   = (const float*)d_in[4];
    const float* wk   = (const float*)d_in[5];
    const float* wv   = (const float*)d_in[6];
    const float* wo   = (const float*)d_in[7];
    const float* bo   = (const float*)d_in[8];
    const float* ln2g = (const float*)d_in[9];
    const float* ln2b = (const float*)d_in[10];
    const float* w1   = (const float*)d_in[11];
    const float* b1   = (const float*)d_in[12];
    const float* w2   = (const float*)d_in[13];
    const float* b2   = (const float*)d_in[14];

    char* p = (char*)d_ws;
    auto alloc = [&](size_t bytes) {
        char* r = p; p += (bytes + 255) & ~(size_t)255; return r;
    };
    u16*  xn    = (u16*)alloc((size_t)BS * D * 2);      // LN1 out -> attn_out -> LN2 out
    u16*  qkv   = (u16*)alloc((size_t)BS * QKV * 2);    // [8192][2304] fused q|k|v
    u16*  Sb    = (u16*)alloc((size_t)B * S * S * 2);   // scores/P, later h [8192][3072]
    u16*  wqkvt = (u16*)alloc((size_t)3 * D * D * 2);   // [2304][768]
    u16*  wot   = (u16*)alloc((size_t)D * D * 2);
    u16*  w1t   = (u16*)alloc((size_t)D * F * 2);       // [3072][768]
    u16*  w2t   = (u16*)alloc((size_t)D * F * 2);       // [768][3072]
    float* xmid = (float*)alloc((size_t)BS * D * 4);
    u16*  vt    = (u16*)xmid;   // [2][768][4096]; dead before xmid is written

    const dim3 tt(32, 8);
    transpose_cast_f32<<<dim3(D/32, D/32, 1), tt, 0, stream>>>(wq, wqkvt,            D, D);
    transpose_cast_f32<<<dim3(D/32, D/32, 1), tt, 0, stream>>>(wk, wqkvt + D * D,    D, D);
    transpose_cast_f32<<<dim3(D/32, D/32, 1), tt, 0, stream>>>(wv, wqkvt + 2 * D * D,D, D);
    transpose_cast_f32<<<dim3(D/32, D/32, 1), tt, 0, stream>>>(wo, wot, D, D);
    transpose_cast_f32<<<dim3(F/32, D/32, 1), tt, 0, stream>>>(w1, w1t, D, F);
    transpose_cast_f32<<<dim3(D/32, F/32, 1), tt, 0, stream>>>(w2, w2t, F, D);

    // LN1
    layernorm_k<<<BS, 256, 0, stream>>>(x, ln1g, ln1b, xn, D);

    // fused QKV: [8192][768] x [2304][768]^T -> [8192][2304]
    gemm256<0><<<dim3(BS/256, QKV/256, 1), 512, 0, stream>>>(
        xn, wqkvt, qkv, nullptr, D, D, QKV, D, 0, 0, 0, 1.f);

    // scores = q @ k^T / sqrt(D)  per batch -> Sb
    const float scl = 0.03608439182435161f;   // 1/sqrt(768)
    gemm256<1><<<dim3(S/256, S/256, B), 512, 0, stream>>>(
        qkv, qkv + D, Sb, nullptr, QKV, QKV, S, D,
        (long)S * QKV, (long)S * QKV, (long)S * S, scl);

    // v^T per batch: qkv v-slice [4096][2304-strided] -> vt [768][4096]
    transpose_b16<<<dim3(D/32, S/32, B), tt, 0, stream>>>(
        qkv + 2 * D, vt, S, D, QKV, (long)S * QKV, (long)D * S);

    // softmax rows in place
    softmax_rows<<<B * S, 256, 0, stream>>>(Sb, S);

    // attn_out = P @ V  -> xn (LN1 out is dead)
    gemm_bt<0><<<dim3(S/128, D/128, B), 256, 0, stream>>>(
        Sb, vt, xn, nullptr, nullptr, nullptr, S, S, D, S,
        (long)S * S, (long)D * S, (long)S * D);

    // x_mid = attn_out @ wo + bo + x  (fp32)
    gemm_bt<2><<<dim3(BS/128, D/128, 1), 256, 0, stream>>>(
        xn, wot, nullptr, xmid, bo, x, D, D, D, D, 0, 0, 0);

    // LN2 -> xn
    layernorm_k<<<BS, 256, 0, stream>>>(xmid, ln2g, ln2b, xn, D);

    // h = gelu(xn @ w1 + b1) -> Sb [8192][3072]
    gemm256<3><<<dim3(BS/256, F/256, 1), 512, 0, stream>>>(
        xn, w1t, Sb, b1, D, D, F, D, 0, 0, 0, 1.f);

    // out = h @ w2 + b2 + xmid  (fp32 -> d_out)
    gemm_bt<2><<<dim3(BS/128, D/128, 1), 256, 0, stream>>>(
        Sb, w2t, nullptr, (float*)d_out, b2, xmid, F, F, D, F, 0, 0, 0);
}

// Round 5
// 439.335 us; speedup vs baseline: 1.0140x; 1.0030x over previous
//
#include <hip/hip_runtime.h>
#include <math.h>

typedef unsigned short u16;
typedef unsigned int   u32;
typedef float  f32x4  __attribute__((ext_vector_type(4)));
typedef __bf16 bf16x8 __attribute__((ext_vector_type(8)));
typedef unsigned short u16x8 __attribute__((ext_vector_type(8)));

__device__ __forceinline__ float bf2f(u16 h) {
    union { u32 u; float f; } v; v.u = ((u32)h) << 16; return v.f;
}
__device__ __forceinline__ u16 f2bf(float f) {
    union { float f; u32 u; } v; v.f = f;
    u32 u = v.u;
    return (u16)((u + 0x7FFFu + ((u >> 16) & 1u)) >> 16);  // RNE
}

// async global->LDS, 16B per lane. LDS dest must be wave-uniform base + lane*16.
__device__ __forceinline__ void gload_lds16(const void* g, void* l) {
    __builtin_amdgcn_global_load_lds((const __attribute__((address_space(1))) void*)g,
                                     (__attribute__((address_space(3))) void*)l,
                                     16, 0, 0);
}

#define SBAR __builtin_amdgcn_sched_barrier(0)
#define WBAR __builtin_amdgcn_s_barrier()
#define MF(a, b, c) __builtin_amdgcn_mfma_f32_16x16x32_bf16((a), (b), (c), 0, 0, 0)

// ---------------------------------------------------------------------------
// 8-phase pipelined 256x256 GEMM, K=768 (NT=12), compile-time strides.
// Round-5 change vs round 4: SAME schedule/ring/vmcnt algebra, but ALL
// addressing is compile-time: LDA/LDB template params, slots are literals
// (tile loop unrolled x2; ring period = 8 units = 2 tiles), ds_read offsets
// precomputed per-lane, staging = 4 persistent pointers bumped +64B.
// Rationale: rounds 2 and 4 (different schedules) showed IDENTICAL
// VALUBusy=35% / MfmaUtil=15.5% -> limiter was runtime address math
// (v_mad_u64 chains, kind-decode branches) on the critical path at
// 2 waves/SIMD, not the schedule.
// Ring (verified r4): unit gu = tile gu>>2, kind gu&1 (0=A,1=B), slot gu&7.
// Stage order from unit 7: B A B A per tile phases P0..P3. vmcnt(6) at tile
// boundary confirms through unit 4t+7 (next tile complete), keeps 3 units
// (6 loads) in flight; drain vmcnt(0) only before the last tile.
// MODE: 0 = store bf16, 1 = store bf16*scale, 3 = store bf16 gelu(acc+bias)
// ---------------------------------------------------------------------------
template<int MODE, int LDA, int LDB>
__global__ __launch_bounds__(512, 2)
void gemm256(const u16* __restrict__ A, const u16* __restrict__ Bt,
             u16* __restrict__ Ob, const float* __restrict__ bias,
             int ldc, long a_bstride, long b_bstride, long c_bstride,
             float scale)
{
    __shared__ __align__(16) u16 lds8[8][8192];   // 8 slots x 16KB

    const int bz = blockIdx.z;
    const u16* Ab = A  + (long)bz * a_bstride;
    const u16* Bb = Bt + (long)bz * b_bstride;
    const long cbase = (long)bz * c_bstride;

    const int tid  = threadIdx.x;
    const int lane = tid & 63;
    const int wid  = tid >> 6;
    const int wm   = wid >> 2;         // 0..1  (128 rows each)
    const int wn   = wid & 3;          // 0..3  (64 cols each)
    const long row0 = (long)blockIdx.x * 256;
    const long col0 = (long)blockIdx.y * 256;
    const int lr = lane & 15;
    const int lk = lane >> 4;
    const int srow = tid >> 2;         // staging row 0..127
    const int sub  = tid & 3;          // staging 16B octet

    // per-lane ds_read element offsets within a slot (swizzled)
    int offA[8], offB[4];
#pragma unroll
    for (int m = 0; m < 8; ++m) {
        const int r = wm * 128 + m * 16 + lr;
        offA[m] = r * 32 + ((lk ^ ((r >> 1) & 3)) * 8);
    }
#pragma unroll
    for (int n = 0; n < 4; ++n) {
        const int r = wn * 64 + n * 16 + lr;
        offB[n] = r * 32 + ((lk ^ ((r >> 1) & 3)) * 8);
    }

    // staging pointers: pre-swizzled global source, linear LDS dest.
    // swizzle octet u0 = sub ^ ((srow>>1)&3): invariant under r+=128 and k+=32.
    const int u0 = sub ^ ((srow >> 1) & 3);
    const u16* pA0 = Ab + (row0 + srow) * (long)LDA + u0 * 8;
    const u16* pA1 = pA0 + (long)128 * LDA;
    const u16* pB0 = Bb + (col0 + srow) * (long)LDB + u0 * 8;
    const u16* pB1 = pB0 + (long)128 * LDB;
    const int sd = srow * 32 + sub * 8;   // element offset in slot (lane*16 bytes)

#define STA(SLOT) do { \
    gload_lds16(pA0, &lds8[SLOT][sd]); \
    gload_lds16(pA1, &lds8[SLOT][sd + 4096]); \
    pA0 += 32; pA1 += 32; } while (0)
#define STB(SLOT) do { \
    gload_lds16(pB0, &lds8[SLOT][sd]); \
    gload_lds16(pB1, &lds8[SLOT][sd + 4096]); \
    pB0 += 32; pB1 += 32; } while (0)
#define RDA(SLOT, m) (*(const bf16x8*)(&lds8[SLOT][0] + offA[m]))
#define RDB(SLOT, n) (*(const bf16x8*)(&lds8[SLOT][0] + offB[n]))
#define MFMA8x2(c0, c1) do { \
    __builtin_amdgcn_s_setprio(1); \
    _Pragma("unroll") \
    for (int m_ = 0; m_ < 8; ++m_) { \
        acc[m_][c0] = MF(af[m_], bq[0], acc[m_][c0]); \
        acc[m_][c1] = MF(af[m_], bq[1], acc[m_][c1]); \
    } \
    __builtin_amdgcn_s_setprio(0); } while (0)

// one K-tile (BK=64): 4 phases. SA0/SB0 = k0 slots, SA1/SB1 = k1 slots.
// ST0..ST3 = staging statements (B,A,B,A pattern), possibly (void)0.
#define TILE(SA0, SB0, SA1, SB1, ST0, ST1, ST2, ST3) do { \
    /* P0: A(k0) m0-7 + B(k0) n0-1 */ \
    _Pragma("unroll") for (int m_ = 0; m_ < 8; ++m_) af[m_] = RDA(SA0, m_); \
    bq[0] = RDB(SB0, 0); bq[1] = RDB(SB0, 1); \
    ST0; \
    SBAR; WBAR; SBAR; \
    MFMA8x2(0, 1); \
    SBAR; WBAR; \
    /* P1: B(k0) n2-3 (A reused in regs) */ \
    bq[0] = RDB(SB0, 2); bq[1] = RDB(SB0, 3); \
    ST1; \
    SBAR; WBAR; SBAR; \
    MFMA8x2(2, 3); \
    SBAR; WBAR; \
    /* P2: A(k1) m0-7 + B(k1) n0-1 */ \
    _Pragma("unroll") for (int m_ = 0; m_ < 8; ++m_) af[m_] = RDA(SA1, m_); \
    bq[0] = RDB(SB1, 0); bq[1] = RDB(SB1, 1); \
    ST2; \
    SBAR; WBAR; SBAR; \
    MFMA8x2(0, 1); \
    SBAR; WBAR; \
    /* P3: B(k1) n2-3 */ \
    bq[0] = RDB(SB1, 2); bq[1] = RDB(SB1, 3); \
    ST3; \
    SBAR; WBAR; SBAR; \
    MFMA8x2(2, 3); \
    SBAR; } while (0)

    f32x4 acc[8][4] = {{}};
    bf16x8 af[8], bq[2];

    // prologue: units 0..6 = A B A B A B A (tile0 + 3/4 of tile1)
    STA(0); STB(1); STA(2); STB(3); STA(4); STB(5); STA(6);
    asm volatile("s_waitcnt vmcnt(6)" ::: "memory");  // 14 issued -> units 0..3 landed
    WBAR; SBAR;

    // tiles 0..9 as 5 unrolled pairs (even slots 0-3 / odd slots 4-7)
#pragma unroll 1
    for (int it = 0; it < 5; ++it) {
        TILE(0, 1, 2, 3, STB(7), STA(0), STB(1), STA(2));
        asm volatile("s_waitcnt vmcnt(6)" ::: "memory"); WBAR; SBAR;
        TILE(4, 5, 6, 7, STB(3), STA(4), STB(5), STA(6));
        asm volatile("s_waitcnt vmcnt(6)" ::: "memory"); WBAR; SBAR;
    }
    // tile 10: stage only unit 47 (last B) at P0
    TILE(0, 1, 2, 3, STB(7), (void)0, (void)0, (void)0);
    asm volatile("s_waitcnt vmcnt(0)" ::: "memory"); WBAR; SBAR;
    // tile 11: no staging
    TILE(4, 5, 6, 7, (void)0, (void)0, (void)0, (void)0);

#undef STA
#undef STB
#undef RDA
#undef RDB
#undef MFMA8x2
#undef TILE

    // epilogue: C/D layout col=lane&15, row=(lane>>4)*4+reg
#pragma unroll
    for (int m = 0; m < 8; ++m) {
#pragma unroll
        for (int n = 0; n < 4; ++n) {
#pragma unroll
            for (int j = 0; j < 4; ++j) {
                const long row = row0 + wm * 128 + m * 16 + lk * 4 + j;
                const long col = col0 + wn * 64 + n * 16 + lr;
                const long idx = cbase + row * (long)ldc + col;
                const float v = acc[m][n][j];
                if (MODE == 0) {
                    Ob[idx] = f2bf(v);
                } else if (MODE == 1) {
                    Ob[idx] = f2bf(v * scale);
                } else {
                    const float tt2 = v + bias[col];
                    Ob[idx] = f2bf(0.5f * tt2 * (1.0f + erff(tt2 * 0.70710678118654752f)));
                }
            }
        }
    }
}

// ---------------------------------------------------------------------------
// 128x128 GEMM (proven structure, stride-parameterized).
// MODE: 0 = store bf16, 2 = f32 acc+bias[col]+res[idx]
// ---------------------------------------------------------------------------
template<int MODE>
__global__ __launch_bounds__(256, 2)
void gemm_bt(const u16* __restrict__ A, const u16* __restrict__ Bt,
             u16* __restrict__ Ob, float* __restrict__ Of,
             const float* __restrict__ bias, const float* __restrict__ res,
             int lda, int ldb, int ldc, int K,
             long a_bstride, long b_bstride, long c_bstride)
{
    __shared__ __align__(16) u16 As[128 * 32];
    __shared__ __align__(16) u16 Bs[128 * 32];

    const int bz = blockIdx.z;
    const u16* Ab = A + (long)bz * a_bstride;
    const u16* Bb = Bt + (long)bz * b_bstride;
    const long cbase = (long)bz * c_bstride;

    const int tid  = threadIdx.x;
    const int lane = tid & 63;
    const int wave = tid >> 6;
    const int wr = (wave >> 1) * 64;
    const int wc = (wave & 1) * 64;
    const long row0 = (long)blockIdx.x * 128;
    const long col0 = (long)blockIdx.y * 128;

    const int lr = lane & 15;
    const int lk = lane >> 4;
    const int srow = tid >> 2;
    const int sub  = tid & 3;

    f32x4 acc[4][4] = {{}};

    for (int k0 = 0; k0 < K; k0 += 32) {
#pragma unroll
        for (int p = 0; p < 2; ++p) {
            const int r = p * 64 + srow;
            const int u = sub ^ ((r >> 1) & 3);          // pre-swizzled source
            gload_lds16(Ab + (row0 + r) * (long)lda + k0 + u * 8, As + r * 32 + sub * 8);
            gload_lds16(Bb + (col0 + r) * (long)ldb + k0 + u * 8, Bs + r * 32 + sub * 8);
        }
        __syncthreads();

        bf16x8 af[4], bfr[4];
#pragma unroll
        for (int m = 0; m < 4; ++m) {
            const int r = wr + m * 16 + lr;
            af[m] = *(const bf16x8*)(As + r * 32 + ((lk ^ ((r >> 1) & 3)) * 8));
        }
#pragma unroll
        for (int n = 0; n < 4; ++n) {
            const int r = wc + n * 16 + lr;
            bfr[n] = *(const bf16x8*)(Bs + r * 32 + ((lk ^ ((r >> 1) & 3)) * 8));
        }
#pragma unroll
        for (int m = 0; m < 4; ++m)
#pragma unroll
            for (int n = 0; n < 4; ++n)
                acc[m][n] = MF(af[m], bfr[n], acc[m][n]);
        __syncthreads();
    }

#pragma unroll
    for (int m = 0; m < 4; ++m) {
#pragma unroll
        for (int n = 0; n < 4; ++n) {
#pragma unroll
            for (int j = 0; j < 4; ++j) {
                const long row = row0 + wr + m * 16 + lk * 4 + j;
                const long col = col0 + wc + n * 16 + lr;
                const long idx = cbase + row * (long)ldc + col;
                const float v = acc[m][n][j];
                if (MODE == 0) {
                    Ob[idx] = f2bf(v);
                } else {
                    Of[idx] = v + bias[col] + res[idx];
                }
            }
        }
    }
}

// ---------------------------------------------------------------------------
// transpose + cast fp32 -> bf16 : in[R][C] -> out[C][R]
// ---------------------------------------------------------------------------
__global__ __launch_bounds__(256)
void transpose_cast_f32(const float* __restrict__ in, u16* __restrict__ out,
                        int R, int C)
{
    __shared__ u16 tile[32][33];
    const int c0 = blockIdx.x * 32, r0 = blockIdx.y * 32;
    const int tx = threadIdx.x, ty = threadIdx.y;   // 32 x 8
#pragma unroll
    for (int j = 0; j < 4; ++j) {
        const int r = ty + j * 8;
        tile[r][tx] = f2bf(in[(long)(r0 + r) * C + c0 + tx]);
    }
    __syncthreads();
#pragma unroll
    for (int j = 0; j < 4; ++j) {
        const int c = ty + j * 8;
        out[(long)(c0 + c) * R + r0 + tx] = tile[tx][c];
    }
}

// bf16 strided transpose with batch: in[z][R][ld_in] -> out[z][C][R]
__global__ __launch_bounds__(256)
void transpose_b16(const u16* __restrict__ in, u16* __restrict__ out,
                   int R, int C, int ld_in, long in_bstride, long out_bstride)
{
    __shared__ u16 tile[32][33];
    in  += (long)blockIdx.z * in_bstride;
    out += (long)blockIdx.z * out_bstride;
    const int c0 = blockIdx.x * 32, r0 = blockIdx.y * 32;
    const int tx = threadIdx.x, ty = threadIdx.y;
#pragma unroll
    for (int j = 0; j < 4; ++j) {
        const int r = ty + j * 8;
        tile[r][tx] = in[(long)(r0 + r) * ld_in + c0 + tx];
    }
    __syncthreads();
#pragma unroll
    for (int j = 0; j < 4; ++j) {
        const int c = ty + j * 8;
        out[(long)(c0 + c) * R + r0 + tx] = tile[tx][c];
    }
}

// ---------------------------------------------------------------------------
// LayerNorm over D=768, one block (256 thr) per row; out bf16.
// ---------------------------------------------------------------------------
__global__ __launch_bounds__(256)
void layernorm_k(const float* __restrict__ x, const float* __restrict__ g,
                 const float* __restrict__ b, u16* __restrict__ out, int D)
{
    const long row = blockIdx.x;
    const float* xr = x + row * D;
    const int tid = threadIdx.x;
    float v[3];
    float s = 0.f, s2 = 0.f;
#pragma unroll
    for (int i = 0; i < 3; ++i) {
        v[i] = xr[tid + i * 256];
        s += v[i]; s2 += v[i] * v[i];
    }
#pragma unroll
    for (int o = 32; o > 0; o >>= 1) {
        s  += __shfl_down(s,  o);
        s2 += __shfl_down(s2, o);
    }
    __shared__ float ps[4], ps2[4], st[2];
    const int wave = tid >> 6, lane = tid & 63;
    if (lane == 0) { ps[wave] = s; ps2[wave] = s2; }
    __syncthreads();
    if (tid == 0) {
        const float a  = ps[0] + ps[1] + ps[2] + ps[3];
        const float a2 = ps2[0] + ps2[1] + ps2[2] + ps2[3];
        const float mu = a / (float)D;
        const float var = a2 / (float)D - mu * mu;
        st[0] = mu;
        st[1] = rsqrtf(var + 1e-8f);
    }
    __syncthreads();
    const float mu = st[0], rs = st[1];
#pragma unroll
    for (int i = 0; i < 3; ++i) {
        const int c = tid + i * 256;
        out[row * D + c] = f2bf((v[i] - mu) * rs * g[c] + b[c]);
    }
}

// ---------------------------------------------------------------------------
// Row softmax in-place over bf16 rows of length 4096, vectorized 16B/lane.
// ---------------------------------------------------------------------------
__global__ __launch_bounds__(256)
void softmax_rows(u16* __restrict__ S, int L)
{
    u16* row = S + (long)blockIdx.x * L;
    const int tid = threadIdx.x;
    const int wave = tid >> 6, lane = tid & 63;
    u16x8 h0 = *(const u16x8*)(row + tid * 16);
    u16x8 h1 = *(const u16x8*)(row + tid * 16 + 8);
    float v[16];
#pragma unroll
    for (int i = 0; i < 8; ++i) { v[i] = bf2f(h0[i]); v[8 + i] = bf2f(h1[i]); }

    float m = -1e30f;
#pragma unroll
    for (int i = 0; i < 16; ++i) m = fmaxf(m, v[i]);
#pragma unroll
    for (int o = 32; o > 0; o >>= 1) m = fmaxf(m, __shfl_xor(m, o));
    __shared__ float pm[4], pl[4];
    if (lane == 0) pm[wave] = m;
    __syncthreads();
    m = fmaxf(fmaxf(pm[0], pm[1]), fmaxf(pm[2], pm[3]));

    float l = 0.f;
#pragma unroll
    for (int i = 0; i < 16; ++i) { v[i] = expf(v[i] - m); l += v[i]; }
#pragma unroll
    for (int o = 32; o > 0; o >>= 1) l += __shfl_xor(l, o);
    if (lane == 0) pl[wave] = l;
    __syncthreads();
    l = pl[0] + pl[1] + pl[2] + pl[3];
    const float inv = 1.0f / l;
#pragma unroll
    for (int i = 0; i < 8; ++i) { h0[i] = f2bf(v[i] * inv); h1[i] = f2bf(v[8 + i] * inv); }
    *(u16x8*)(row + tid * 16)     = h0;
    *(u16x8*)(row + tid * 16 + 8) = h1;
}

// ---------------------------------------------------------------------------
extern "C" void kernel_launch(void* const* d_in, const int* in_sizes, int n_in,
                              void* d_out, int out_size, void* d_ws, size_t ws_size,
                              hipStream_t stream)
{
    (void)in_sizes; (void)n_in; (void)out_size; (void)ws_size;
    const int B = 2, S = 4096, D = 768, F = 3072;
    const int BS = B * S;                       // 8192
    const int QKV = 3 * D;                      // 2304

    const float* x    = (const float*)d_in[0];
    // d_in[1] = mask: all ones -> no-op
    const float* ln1g = (const float*)d_in[2];
    const float* ln1b = (const float*)d_in[3];
    const float* wq   = (const float*)d_in[4];
    const float* wk   = (const float*)d_in[5];
    const float* wv   = (const float*)d_in[6];
    const float* wo   = (const float*)d_in[7];
    const float* bo   = (const float*)d_in[8];
    const float* ln2g = (const float*)d_in[9];
    const float* ln2b = (const float*)d_in[10];
    const float* w1   = (const float*)d_in[11];
    const float* b1   = (const float*)d_in[12];
    const float* w2   = (const float*)d_in[13];
    const float* b2   = (const float*)d_in[14];

    char* p = (char*)d_ws;
    auto alloc = [&](size_t bytes) {
        char* r = p; p += (bytes + 255) & ~(size_t)255; return r;
    };
    u16*  xn    = (u16*)alloc((size_t)BS * D * 2);      // LN1 out -> attn_out -> LN2 out
    u16*  qkv   = (u16*)alloc((size_t)BS * QKV * 2);    // [8192][2304] fused q|k|v
    u16*  Sb    = (u16*)alloc((size_t)B * S * S * 2);   // scores/P, later h [8192][3072]
    u16*  wqkvt = (u16*)alloc((size_t)3 * D * D * 2);   // [2304][768]
    u16*  wot   = (u16*)alloc((size_t)D * D * 2);
    u16*  w1t   = (u16*)alloc((size_t)D * F * 2);       // [3072][768]
    u16*  w2t   = (u16*)alloc((size_t)D * F * 2);       // [768][3072]
    float* xmid = (float*)alloc((size_t)BS * D * 4);
    u16*  vt    = (u16*)xmid;   // [2][768][4096]; dead before xmid is written

    const dim3 tt(32, 8);
    transpose_cast_f32<<<dim3(D/32, D/32, 1), tt, 0, stream>>>(wq, wqkvt,            D, D);
    transpose_cast_f32<<<dim3(D/32, D/32, 1), tt, 0, stream>>>(wk, wqkvt + D * D,    D, D);
    transpose_cast_f32<<<dim3(D/32, D/32, 1), tt, 0, stream>>>(wv, wqkvt + 2 * D * D,D, D);
    transpose_cast_f32<<<dim3(D/32, D/32, 1), tt, 0, stream>>>(wo, wot, D, D);
    transpose_cast_f32<<<dim3(F/32, D/32, 1), tt, 0, stream>>>(w1, w1t, D, F);
    transpose_cast_f32<<<dim3(D/32, F/32, 1), tt, 0, stream>>>(w2, w2t, F, D);

    // LN1
    layernorm_k<<<BS, 256, 0, stream>>>(x, ln1g, ln1b, xn, D);

    // fused QKV: [8192][768] x [2304][768]^T -> [8192][2304]
    gemm256<0, 768, 768><<<dim3(BS/256, QKV/256, 1), 512, 0, stream>>>(
        xn, wqkvt, qkv, nullptr, QKV, 0, 0, 0, 1.f);

    // scores = q @ k^T / sqrt(D)  per batch -> Sb
    const float scl = 0.03608439182435161f;   // 1/sqrt(768)
    gemm256<1, 2304, 2304><<<dim3(S/256, S/256, B), 512, 0, stream>>>(
        qkv, qkv + D, Sb, nullptr, S,
        (long)S * QKV, (long)S * QKV, (long)S * S, scl);

    // v^T per batch: qkv v-slice [4096][2304-strided] -> vt [768][4096]
    transpose_b16<<<dim3(D/32, S/32, B), tt, 0, stream>>>(
        qkv + 2 * D, vt, S, D, QKV, (long)S * QKV, (long)D * S);

    // softmax rows in place
    softmax_rows<<<B * S, 256, 0, stream>>>(Sb, S);

    // attn_out = P @ V  -> xn (LN1 out is dead)
    gemm_bt<0><<<dim3(S/128, D/128, B), 256, 0, stream>>>(
        Sb, vt, xn, nullptr, nullptr, nullptr, S, S, D, S,
        (long)S * S, (long)D * S, (long)S * D);

    // x_mid = attn_out @ wo + bo + x  (fp32)
    gemm_bt<2><<<dim3(BS/128, D/128, 1), 256, 0, stream>>>(
        xn, wot, nullptr, xmid, bo, x, D, D, D, D, 0, 0, 0);

    // LN2 -> xn
    layernorm_k<<<BS, 256, 0, stream>>>(xmid, ln2g, ln2b, xn, D);

    // h = gelu(xn @ w1 + b1) -> Sb [8192][3072]
    gemm256<3, 768, 768><<<dim3(BS/256, F/256, 1), 512, 0, stream>>>(
        xn, w1t, Sb, b1, F, 0, 0, 0, 1.f);

    // out = h @ w2 + b2 + xmid  (fp32 -> d_out)
    gemm_bt<2><<<dim3(BS/128, D/128, 1), 256, 0, stream>>>(
        Sb, w2t, nullptr, (float*)d_out, b2, xmid, F, F, D, F, 0, 0, 0);
}

// Round 6
// 408.998 us; speedup vs baseline: 1.0892x; 1.0742x over previous
//
#include <hip/hip_runtime.h>
#include <math.h>

typedef unsigned short u16;
typedef unsigned int   u32;
typedef float  f32x4  __attribute__((ext_vector_type(4)));
typedef __bf16 bf16x8 __attribute__((ext_vector_type(8)));
typedef unsigned short u16x8 __attribute__((ext_vector_type(8)));

__device__ __forceinline__ float bf2f(u16 h) {
    union { u32 u; float f; } v; v.u = ((u32)h) << 16; return v.f;
}
__device__ __forceinline__ u16 f2bf(float f) {
    union { float f; u32 u; } v; v.f = f;
    u32 u = v.u;
    return (u16)((u + 0x7FFFu + ((u >> 16) & 1u)) >> 16);  // RNE
}

// async global->LDS, 16B per lane. LDS dest must be wave-uniform base + lane*16.
__device__ __forceinline__ void gload_lds16(const void* g, void* l) {
    __builtin_amdgcn_global_load_lds((const __attribute__((address_space(1))) void*)g,
                                     (__attribute__((address_space(3))) void*)l,
                                     16, 0, 0);
}

#define MF(a, b, c) __builtin_amdgcn_mfma_f32_16x16x32_bf16((a), (b), (c), 0, 0, 0)

// ---------------------------------------------------------------------------
// 128x128 GEMM, C[M][N] = A[M][K] * Bt[N][K]^T (bf16 in, proven structure).
// 4 waves (2x2), per-wave 64x64 = 4x4 frags of 16x16x32; BK=32;
// global_load_lds width-16 staging with k-octet XOR swizzle (pre-swizzled
// global source, same XOR on ds_read -> <=2-way bank aliasing, free).
// This kernel consistently outperformed the 256x256 pipelined variants
// (rounds 2-5: ~570 TF vs ~420 TF) -- all GEMMs now run on it.
// MODE: 0 = store bf16
//       1 = store bf16 * scale
//       2 = store f32  acc + bias[col] + res[idx]
//       3 = store bf16 gelu(acc + bias[col])   (exact erf GELU)
// ---------------------------------------------------------------------------
template<int MODE>
__global__ __launch_bounds__(256, 2)
void gemm_bt(const u16* __restrict__ A, const u16* __restrict__ Bt,
             u16* __restrict__ Ob, float* __restrict__ Of,
             const float* __restrict__ bias, const float* __restrict__ res,
             int lda, int ldb, int ldc, int K,
             long a_bstride, long b_bstride, long c_bstride, float scale)
{
    __shared__ __align__(16) u16 As[128 * 32];
    __shared__ __align__(16) u16 Bs[128 * 32];

    const int bz = blockIdx.z;
    const u16* Ab = A + (long)bz * a_bstride;
    const u16* Bb = Bt + (long)bz * b_bstride;
    const long cbase = (long)bz * c_bstride;

    const int tid  = threadIdx.x;
    const int lane = tid & 63;
    const int wave = tid >> 6;
    const int wr = (wave >> 1) * 64;
    const int wc = (wave & 1) * 64;
    const long row0 = (long)blockIdx.x * 128;
    const long col0 = (long)blockIdx.y * 128;

    const int lr = lane & 15;
    const int lk = lane >> 4;
    const int srow = tid >> 2;
    const int sub  = tid & 3;

    f32x4 acc[4][4] = {{}};

    for (int k0 = 0; k0 < K; k0 += 32) {
#pragma unroll
        for (int p = 0; p < 2; ++p) {
            const int r = p * 64 + srow;
            const int u = sub ^ ((r >> 1) & 3);          // pre-swizzled source
            gload_lds16(Ab + (row0 + r) * (long)lda + k0 + u * 8, As + r * 32 + sub * 8);
            gload_lds16(Bb + (col0 + r) * (long)ldb + k0 + u * 8, Bs + r * 32 + sub * 8);
        }
        __syncthreads();

        bf16x8 af[4], bfr[4];
#pragma unroll
        for (int m = 0; m < 4; ++m) {
            const int r = wr + m * 16 + lr;
            af[m] = *(const bf16x8*)(As + r * 32 + ((lk ^ ((r >> 1) & 3)) * 8));
        }
#pragma unroll
        for (int n = 0; n < 4; ++n) {
            const int r = wc + n * 16 + lr;
            bfr[n] = *(const bf16x8*)(Bs + r * 32 + ((lk ^ ((r >> 1) & 3)) * 8));
        }
#pragma unroll
        for (int m = 0; m < 4; ++m)
#pragma unroll
            for (int n = 0; n < 4; ++n)
                acc[m][n] = MF(af[m], bfr[n], acc[m][n]);
        __syncthreads();
    }

    // C/D layout (verified): col = lane&15, row = (lane>>4)*4 + reg
#pragma unroll
    for (int m = 0; m < 4; ++m) {
#pragma unroll
        for (int n = 0; n < 4; ++n) {
#pragma unroll
            for (int j = 0; j < 4; ++j) {
                const long row = row0 + wr + m * 16 + lk * 4 + j;
                const long col = col0 + wc + n * 16 + lr;
                const long idx = cbase + row * (long)ldc + col;
                const float v = acc[m][n][j];
                if (MODE == 0) {
                    Ob[idx] = f2bf(v);
                } else if (MODE == 1) {
                    Ob[idx] = f2bf(v * scale);
                } else if (MODE == 2) {
                    Of[idx] = v + bias[col] + res[idx];
                } else {
                    const float t = v + bias[col];
                    Ob[idx] = f2bf(0.5f * t * (1.0f + erff(t * 0.70710678118654752f)));
                }
            }
        }
    }
}

// ---------------------------------------------------------------------------
// transpose + cast fp32 -> bf16 : in[R][C] -> out[C][R]
// ---------------------------------------------------------------------------
__global__ __launch_bounds__(256)
void transpose_cast_f32(const float* __restrict__ in, u16* __restrict__ out,
                        int R, int C)
{
    __shared__ u16 tile[32][33];
    const int c0 = blockIdx.x * 32, r0 = blockIdx.y * 32;
    const int tx = threadIdx.x, ty = threadIdx.y;   // 32 x 8
#pragma unroll
    for (int j = 0; j < 4; ++j) {
        const int r = ty + j * 8;
        tile[r][tx] = f2bf(in[(long)(r0 + r) * C + c0 + tx]);
    }
    __syncthreads();
#pragma unroll
    for (int j = 0; j < 4; ++j) {
        const int c = ty + j * 8;
        out[(long)(c0 + c) * R + r0 + tx] = tile[tx][c];
    }
}

// ---------------------------------------------------------------------------
// LayerNorm over D=768, one block (256 thr) per row; out bf16.
// ---------------------------------------------------------------------------
__global__ __launch_bounds__(256)
void layernorm_k(const float* __restrict__ x, const float* __restrict__ g,
                 const float* __restrict__ b, u16* __restrict__ out, int D)
{
    const long row = blockIdx.x;
    const float* xr = x + row * D;
    const int tid = threadIdx.x;
    float v[3];
    float s = 0.f, s2 = 0.f;
#pragma unroll
    for (int i = 0; i < 3; ++i) {
        v[i] = xr[tid + i * 256];
        s += v[i]; s2 += v[i] * v[i];
    }
#pragma unroll
    for (int o = 32; o > 0; o >>= 1) {
        s  += __shfl_down(s,  o);
        s2 += __shfl_down(s2, o);
    }
    __shared__ float ps[4], ps2[4], st[2];
    const int wave = tid >> 6, lane = tid & 63;
    if (lane == 0) { ps[wave] = s; ps2[wave] = s2; }
    __syncthreads();
    if (tid == 0) {
        const float a  = ps[0] + ps[1] + ps[2] + ps[3];
        const float a2 = ps2[0] + ps2[1] + ps2[2] + ps2[3];
        const float mu = a / (float)D;
        const float var = a2 / (float)D - mu * mu;
        st[0] = mu;
        st[1] = rsqrtf(var + 1e-8f);
    }
    __syncthreads();
    const float mu = st[0], rs = st[1];
#pragma unroll
    for (int i = 0; i < 3; ++i) {
        const int c = tid + i * 256;
        out[row * D + c] = f2bf((v[i] - mu) * rs * g[c] + b[c]);
    }
}

// ---------------------------------------------------------------------------
// Row softmax in-place over bf16 rows of length 4096, 16B/lane vectorized,
// __expf (v_exp_f32) for the exponential.
// ---------------------------------------------------------------------------
__global__ __launch_bounds__(256)
void softmax_rows(u16* __restrict__ S, int L)
{
    u16* row = S + (long)blockIdx.x * L;
    const int tid = threadIdx.x;
    const int wave = tid >> 6, lane = tid & 63;
    u16x8 h0 = *(const u16x8*)(row + tid * 16);
    u16x8 h1 = *(const u16x8*)(row + tid * 16 + 8);
    float v[16];
#pragma unroll
    for (int i = 0; i < 8; ++i) { v[i] = bf2f(h0[i]); v[8 + i] = bf2f(h1[i]); }

    float m = -1e30f;
#pragma unroll
    for (int i = 0; i < 16; ++i) m = fmaxf(m, v[i]);
#pragma unroll
    for (int o = 32; o > 0; o >>= 1) m = fmaxf(m, __shfl_xor(m, o));
    __shared__ float pm[4], pl[4];
    if (lane == 0) pm[wave] = m;
    __syncthreads();
    m = fmaxf(fmaxf(pm[0], pm[1]), fmaxf(pm[2], pm[3]));

    float l = 0.f;
#pragma unroll
    for (int i = 0; i < 16; ++i) { v[i] = __expf(v[i] - m); l += v[i]; }
#pragma unroll
    for (int o = 32; o > 0; o >>= 1) l += __shfl_xor(l, o);
    if (lane == 0) pl[wave] = l;
    __syncthreads();
    l = pl[0] + pl[1] + pl[2] + pl[3];
    const float inv = 1.0f / l;
#pragma unroll
    for (int i = 0; i < 8; ++i) { h0[i] = f2bf(v[i] * inv); h1[i] = f2bf(v[8 + i] * inv); }
    *(u16x8*)(row + tid * 16)     = h0;
    *(u16x8*)(row + tid * 16 + 8) = h1;
}

// ---------------------------------------------------------------------------
extern "C" void kernel_launch(void* const* d_in, const int* in_sizes, int n_in,
                              void* d_out, int out_size, void* d_ws, size_t ws_size,
                              hipStream_t stream)
{
    (void)in_sizes; (void)n_in; (void)out_size; (void)ws_size;
    const int B = 2, S = 4096, D = 768, F = 3072;
    const int BS = B * S;                       // 8192
    const int QKV = 3 * D;                      // 2304

    const float* x    = (const float*)d_in[0];
    // d_in[1] = mask: all ones -> no-op
    const float* ln1g = (const float*)d_in[2];
    const float* ln1b = (const float*)d_in[3];
    const float* wq   = (const float*)d_in[4];
    const float* wk   = (const float*)d_in[5];
    const float* wv   = (const float*)d_in[6];
    const float* wo   = (const float*)d_in[7];
    const float* bo   = (const float*)d_in[8];
    const float* ln2g = (const float*)d_in[9];
    const float* ln2b = (const float*)d_in[10];
    const float* w1   = (const float*)d_in[11];
    const float* b1   = (const float*)d_in[12];
    const float* w2   = (const float*)d_in[13];
    const float* b2   = (const float*)d_in[14];

    char* p = (char*)d_ws;
    auto alloc = [&](size_t bytes) {
        char* r = p; p += (bytes + 255) & ~(size_t)255; return r;
    };
    u16*  xn    = (u16*)alloc((size_t)BS * D * 2);      // LN1 out -> vwT -> LN2 out
    u16*  qkv   = (u16*)alloc((size_t)BS * QKV * 2);    // [8192][2304] fused q|k|v
    u16*  Sb    = (u16*)alloc((size_t)B * S * S * 2);   // scores/P, later h [8192][3072]
    u16*  wqkvt = (u16*)alloc((size_t)3 * D * D * 2);   // [2304][768]
    u16*  wot   = (u16*)alloc((size_t)D * D * 2);       // Wo^T [768][768]
    u16*  w1t   = (u16*)alloc((size_t)D * F * 2);       // [3072][768]
    u16*  w2t   = (u16*)alloc((size_t)D * F * 2);       // [768][3072]
    float* xmid = (float*)alloc((size_t)BS * D * 4);
    // vwT = (V @ Wo)^T per batch, [2][768][4096] bf16 = 12.58 MB.
    // Aliases xn: LN1-out is dead after QKV; LN2 rewrites xn after PV reads vwT.
    u16*  vwT   = xn;

    const dim3 tt(32, 8);
    transpose_cast_f32<<<dim3(D/32, D/32, 1), tt, 0, stream>>>(wq, wqkvt,             D, D);
    transpose_cast_f32<<<dim3(D/32, D/32, 1), tt, 0, stream>>>(wk, wqkvt + D * D,     D, D);
    transpose_cast_f32<<<dim3(D/32, D/32, 1), tt, 0, stream>>>(wv, wqkvt + 2 * D * D, D, D);
    transpose_cast_f32<<<dim3(D/32, D/32, 1), tt, 0, stream>>>(wo, wot, D, D);
    transpose_cast_f32<<<dim3(F/32, D/32, 1), tt, 0, stream>>>(w1, w1t, D, F);
    transpose_cast_f32<<<dim3(D/32, F/32, 1), tt, 0, stream>>>(w2, w2t, F, D);

    // LN1
    layernorm_k<<<BS, 256, 0, stream>>>(x, ln1g, ln1b, xn, D);

    // fused QKV: [8192][768] x [2304][768]^T -> qkv [8192][2304]
    gemm_bt<0><<<dim3(BS/128, QKV/128, 1), 256, 0, stream>>>(
        xn, wqkvt, qkv, nullptr, nullptr, nullptr,
        D, D, QKV, D, 0, 0, 0, 1.f);

    // scores = q @ k^T / sqrt(D)  per batch -> Sb [4096][4096]
    const float scl = 0.03608439182435161f;   // 1/sqrt(768)
    gemm_bt<1><<<dim3(S/128, S/128, B), 256, 0, stream>>>(
        qkv, qkv + D, Sb, nullptr, nullptr, nullptr,
        QKV, QKV, S, D,
        (long)S * QKV, (long)S * QKV, (long)S * S, scl);

    // vwT = (V @ Wo)^T = Wo^T @ V^T  per batch -> [768][4096]
    //   C[c][s] = sum_k wot[c][k] * V[s][k];  A = wot (lda=768),
    //   Bt = v-slice of qkv (ldb=2304), ldc = 4096.
    gemm_bt<0><<<dim3(D/128, S/128, B), 256, 0, stream>>>(
        wot, qkv + 2 * D, vwT, nullptr, nullptr, nullptr,
        D, QKV, S, D,
        0, (long)S * QKV, (long)D * S, 1.f);

    // softmax rows in place -> P
    softmax_rows<<<B * S, 256, 0, stream>>>(Sb, S);

    // x_mid = P @ vwT^T + bo + x   (Wo folded into PV; f32 out)
    gemm_bt<2><<<dim3(S/128, D/128, B), 256, 0, stream>>>(
        Sb, vwT, nullptr, xmid, bo, x,
        S, S, D, S,
        (long)S * S, (long)D * S, (long)S * D, 1.f);

    // LN2 -> xn (overwrites vwT, which is dead now)
    layernorm_k<<<BS, 256, 0, stream>>>(xmid, ln2g, ln2b, xn, D);

    // h = gelu(xn @ w1 + b1) -> Sb [8192][3072]
    gemm_bt<3><<<dim3(BS/128, F/128, 1), 256, 0, stream>>>(
        xn, w1t, Sb, nullptr, b1, nullptr,
        D, D, F, D, 0, 0, 0, 1.f);

    // out = h @ w2 + b2 + xmid  (f32 -> d_out)
    gemm_bt<2><<<dim3(BS/128, D/128, 1), 256, 0, stream>>>(
        Sb, w2t, nullptr, (float*)d_out, b2, xmid,
        F, F, D, F, 0, 0, 0, 1.f);
}